// Round 2
// baseline (6522.951 us; speedup 1.0000x reference)
//
#include <hip/hip_runtime.h>
#include <hip/hip_bf16.h>
#include <cstdint>
#include <type_traits>

// ---------------------------------------------------------------------------
// Qwen3.5 GatedDeltaNet — round 2: fp32 compute, bf16 big intermediates
// (workspace ~161 MiB; round-1 crash was a workspace overflow at ~321 MiB).
// Pipeline:
//   1) gemm (fp32 in, bf16 out): mixed = hs @ w_qkv    (4096 x 8192 x 2048)
//   2) gemm (fp32 in, bf16 out): z     = hs @ w_z      (4096 x 4096 x 2048)
//   3) ba_kernel: beta = sigmoid(hs@w_b), eg = exp(-exp(A_log)*softplus(hs@w_a+dt_bias))
//   4) conv_kernel: causal depthwise conv(K=4) + silu + per-head l2norm -> qkv (bf16)
//   5) recur_kernel: sequential gated delta rule -> o (fp32, aliases mixed)
//   6) gnorm_kernel: o *= silu(z); RMSNorm(128)*gamma
//   7) gemm (fp32 in, fp32 out): out = o @ w_out       (4096 x 2048 x 4096)
// ---------------------------------------------------------------------------

#define HSZ 2048
#define NUM_K_HEADS 16
#define NUM_V_HEADS 32
#define DKH 128
#define DVH 128
#define KEY_DIM 2048
#define VALUE_DIM 4096
#define CONV_DIM 8192
#define BB 2
#define SSEQ 2048
#define MM (BB * SSEQ) /* 4096 rows */

typedef __hip_bfloat16 bf16;

__device__ __forceinline__ float bfu(ushort u) {
  union { float f; uint32_t i; } x;
  x.i = ((uint32_t)u) << 16;
  return x.f;
}
__device__ __forceinline__ ushort f2b(float f) {
  bf16 h = __float2bfloat16(f);
  return *reinterpret_cast<ushort*>(&h);
}

// ---------------- fp32 tiled GEMM: C[M,N] = A[M,K] @ W[K,N] ----------------
// 64x64 tile, BK=16, 256 threads, 4x4 per thread. OT = float or bf16.
template <typename OT>
__global__ __launch_bounds__(256) void gemm_f32_o(
    const float* __restrict__ A, const float* __restrict__ W,
    OT* __restrict__ C, int M, int N, int K) {
  __shared__ __align__(16) float As[16][68];
  __shared__ __align__(16) float Bs[16][68];
  const int bx = blockIdx.x, by = blockIdx.y;
  const int t = threadIdx.x;
  const int tx = t & 15, ty = t >> 4;
  const int ak = t & 15, am = t >> 4;   // A-load: k, base m
  const int bn = t & 63, bk = t >> 6;   // B-load: n, base k
  float acc[4][4] = {};
  for (int k0 = 0; k0 < K; k0 += 16) {
#pragma unroll
    for (int i = 0; i < 4; ++i)
      As[ak][am + 16 * i] = A[(size_t)(by * 64 + am + 16 * i) * K + k0 + ak];
#pragma unroll
    for (int i = 0; i < 4; ++i)
      Bs[bk + 4 * i][bn] = W[(size_t)(k0 + bk + 4 * i) * N + bx * 64 + bn];
    __syncthreads();
#pragma unroll
    for (int kk = 0; kk < 16; ++kk) {
      float4 av = *(const float4*)&As[kk][ty * 4];
      float4 bv = *(const float4*)&Bs[kk][tx * 4];
      float a[4] = {av.x, av.y, av.z, av.w};
      float b[4] = {bv.x, bv.y, bv.z, bv.w};
#pragma unroll
      for (int i = 0; i < 4; ++i)
#pragma unroll
        for (int j = 0; j < 4; ++j) acc[i][j] += a[i] * b[j];
    }
    __syncthreads();
  }
#pragma unroll
  for (int i = 0; i < 4; ++i) {
    const size_t off = (size_t)(by * 64 + ty * 4 + i) * N + bx * 64 + tx * 4;
    if constexpr (std::is_same_v<OT, float>) {
      float4 v = {acc[i][0], acc[i][1], acc[i][2], acc[i][3]};
      *(float4*)&C[off] = v;
    } else {
      ushort4 u;
      u.x = f2b(acc[i][0]);
      u.y = f2b(acc[i][1]);
      u.z = f2b(acc[i][2]);
      u.w = f2b(acc[i][3]);
      *(ushort4*)&C[off] = u;
    }
  }
}

// ---------------- b/a projections + gates ----------------------------------
__global__ __launch_bounds__(256) void ba_kernel(
    const float* __restrict__ hs, const float* __restrict__ w_b,
    const float* __restrict__ w_a, const float* __restrict__ dt_bias,
    const float* __restrict__ A_log, float* __restrict__ eg,
    float* __restrict__ beta) {
  const int row = blockIdx.x;  // 0..4095
  const int t = threadIdx.x;   // 256
  __shared__ float hsrow[HSZ];
  __shared__ float rb[256], ra[256];
  for (int c = t; c < HSZ; c += 256) hsrow[c] = hs[(size_t)row * HSZ + c];
  __syncthreads();
  const int h = t & 31, p = t >> 5;  // head, partial index (8 partials)
  float sb = 0.f, sa = 0.f;
  const int kbeg = p * 256;
  for (int k = kbeg; k < kbeg + 256; ++k) {
    float x = hsrow[k];
    sb += x * w_b[k * NUM_V_HEADS + h];
    sa += x * w_a[k * NUM_V_HEADS + h];
  }
  rb[t] = sb;
  ra[t] = sa;
  __syncthreads();
  if (t < NUM_V_HEADS) {
    float b = 0.f, a = 0.f;
#pragma unroll
    for (int q = 0; q < 8; ++q) {
      b += rb[t + 32 * q];
      a += ra[t + 32 * q];
    }
    float bet = 1.f / (1.f + expf(-b));
    float x = a + dt_bias[t];
    float sp = (x > 20.f) ? x : log1pf(expf(x));
    float g = -expf(A_log[t]) * sp;
    eg[(size_t)row * NUM_V_HEADS + t] = expf(g);
    beta[(size_t)row * NUM_V_HEADS + t] = bet;
  }
}

// ---------------- causal conv + silu + l2norm (bf16 in/out) ----------------
__global__ __launch_bounds__(256) void conv_kernel(
    const ushort* __restrict__ mixed, const float* __restrict__ conv_w,
    ushort* __restrict__ qkv) {
  const int row = blockIdx.x;  // b*S + s
  const int s = row & (SSEQ - 1);
  const int t = threadIdx.x;
  __shared__ float buf[CONV_DIM];
  const ushort* mrow = mixed + (size_t)row * CONV_DIM;
  for (int c = t; c < CONV_DIM; c += 256) {
    float accv = 0.f;
#pragma unroll
    for (int j = 0; j < 4; ++j) {
      int ds = s - 3 + j;
      if (ds >= 0)
        accv += bfu(mrow[(ptrdiff_t)(ds - s) * CONV_DIM + c]) * conv_w[c * 4 + j];
    }
    buf[c] = accv / (1.f + expf(-accv));  // silu
  }
  __syncthreads();
  // l2norm over the 32 q/k heads (channels 0..4095), groups of 128
  const int grp = t >> 3, r = t & 7;  // 32 groups x 8 lanes
  const float* gp = buf + grp * DKH + r * 16;
  float ssq = 0.f;
#pragma unroll
  for (int i = 0; i < 16; ++i) {
    float x = gp[i];
    ssq += x * x;
  }
  ssq += __shfl_xor(ssq, 1, 64);
  ssq += __shfl_xor(ssq, 2, 64);
  ssq += __shfl_xor(ssq, 4, 64);
  float sc = rsqrtf(ssq + 1e-6f);
  if (grp < 16) sc *= 0.08838834764831845f;  // q gets DK^-0.5
  ushort* orow = qkv + (size_t)row * CONV_DIM;
#pragma unroll
  for (int i = 0; i < 16; ++i)
    orow[grp * DKH + r * 16 + i] = f2b(gp[i] * sc);
  for (int c = 2 * KEY_DIM + t; c < CONV_DIM; c += 256)
    orow[c] = f2b(buf[c]);  // v passthrough
}

// ---------------- sequential gated delta rule ------------------------------
// grid = B * Hv * 4 (dv split in quarters of 32); 256 thr: tk(16) x tv(16)
__global__ __launch_bounds__(256) void recur_kernel(
    const ushort* __restrict__ qkv, const float* __restrict__ eg,
    const float* __restrict__ beta, float* __restrict__ o) {
  const int bid = blockIdx.x;
  const int dvq = bid & 3;
  const int h = (bid >> 2) & 31;
  const int b = bid >> 7;
  const int t = threadIdx.x;
  const int tk = t & 15;
  const int tv = t >> 4;
  const int hk = h >> 1;  // GQA: nrep=2

  const ushort* qp = qkv + (size_t)(b * SSEQ) * CONV_DIM + hk * DKH + tk * 8;
  const ushort* kp = qp + KEY_DIM;
  const ushort* vp = qkv + (size_t)(b * SSEQ) * CONV_DIM + 2 * KEY_DIM + h * DVH + dvq * 32 + tv * 2;
  const float* egp = eg + (size_t)(b * SSEQ) * NUM_V_HEADS + h;
  const float* bp = beta + (size_t)(b * SSEQ) * NUM_V_HEADS + h;
  float* op = o + (size_t)(b * SSEQ) * VALUE_DIM + h * DVH + dvq * 32 + tv * 2;

  float st0[8], st1[8];
#pragma unroll
  for (int i = 0; i < 8; ++i) {
    st0[i] = 0.f;
    st1[i] = 0.f;
  }

  for (int s = 0; s < SSEQ; ++s) {
    const size_t ro = (size_t)s * CONV_DIM;
    ushort4 qa = *(const ushort4*)(qp + ro);
    ushort4 qb = *(const ushort4*)(qp + ro + 4);
    ushort4 ka = *(const ushort4*)(kp + ro);
    ushort4 kb = *(const ushort4*)(kp + ro + 4);
    ushort2 vv = *(const ushort2*)(vp + ro);
    float e = egp[(size_t)s * NUM_V_HEADS];
    float bt = bp[(size_t)s * NUM_V_HEADS];
    float kf[8] = {bfu(ka.x), bfu(ka.y), bfu(ka.z), bfu(ka.w),
                   bfu(kb.x), bfu(kb.y), bfu(kb.z), bfu(kb.w)};
    float qf[8] = {bfu(qa.x), bfu(qa.y), bfu(qa.z), bfu(qa.w),
                   bfu(qb.x), bfu(qb.y), bfu(qb.z), bfu(qb.w)};
    float kv0 = 0.f, kv1 = 0.f;
#pragma unroll
    for (int i = 0; i < 8; ++i) {
      st0[i] *= e;
      st1[i] *= e;
      kv0 += kf[i] * st0[i];
      kv1 += kf[i] * st1[i];
    }
#pragma unroll
    for (int w = 1; w < 16; w <<= 1) {
      kv0 += __shfl_xor(kv0, w, 64);
      kv1 += __shfl_xor(kv1, w, 64);
    }
    float d0 = (bfu(vv.x) - kv0) * bt;
    float d1 = (bfu(vv.y) - kv1) * bt;
    float o0 = 0.f, o1 = 0.f;
#pragma unroll
    for (int i = 0; i < 8; ++i) {
      st0[i] += kf[i] * d0;
      o0 += qf[i] * st0[i];
      st1[i] += kf[i] * d1;
      o1 += qf[i] * st1[i];
    }
#pragma unroll
    for (int w = 1; w < 16; w <<= 1) {
      o0 += __shfl_xor(o0, w, 64);
      o1 += __shfl_xor(o1, w, 64);
    }
    if (tk == 0) {
      op[(size_t)s * VALUE_DIM + 0] = o0;
      op[(size_t)s * VALUE_DIM + 1] = o1;
    }
  }
}

// ---------------- gated RMSNorm (z in bf16) --------------------------------
__global__ __launch_bounds__(256) void gnorm_kernel(
    float* __restrict__ o, const ushort* __restrict__ z,
    const float* __restrict__ gamma) {
  const int row = blockIdx.x;
  const int t = threadIdx.x;
  const int grp = t >> 3, r = t & 7;  // 32 heads x 8 lanes
  float* op = o + (size_t)row * VALUE_DIM + grp * DVH + r * 16;
  const ushort* zp = z + (size_t)row * VALUE_DIM + grp * DVH + r * 16;
  float vals[16];
  float ssq = 0.f;
#pragma unroll
  for (int i = 0; i < 16; ++i) {
    float zz = bfu(zp[i]);
    float x = op[i] * (zz / (1.f + expf(-zz)));
    vals[i] = x;
    ssq += x * x;
  }
  ssq += __shfl_xor(ssq, 1, 64);
  ssq += __shfl_xor(ssq, 2, 64);
  ssq += __shfl_xor(ssq, 4, 64);
  float sc = rsqrtf(ssq * (1.f / 128.f) + 1e-6f);
#pragma unroll
  for (int i = 0; i < 16; ++i) op[i] = vals[i] * sc * gamma[r * 16 + i];
}

// ---------------------------------------------------------------------------
extern "C" void kernel_launch(void* const* d_in, const int* in_sizes, int n_in,
                              void* d_out, int out_size, void* d_ws,
                              size_t ws_size, hipStream_t stream) {
  const float* hs = (const float*)d_in[0];
  const float* w_qkv = (const float*)d_in[1];
  const float* w_z = (const float*)d_in[2];
  const float* w_b = (const float*)d_in[3];
  const float* w_a = (const float*)d_in[4];
  const float* conv_w = (const float*)d_in[5];
  const float* dt_bias = (const float*)d_in[6];
  const float* A_log = (const float*)d_in[7];
  const float* gamma = (const float*)d_in[8];
  const float* w_out = (const float*)d_in[9];
  float* out = (float*)d_out;
  char* wsb = (char*)d_ws;

  // workspace layout (bytes): total ~161 MiB
  const size_t MIXED_B = (size_t)MM * CONV_DIM * 2;   // 64 MiB (bf16)
  const size_t QKV_B   = (size_t)MM * CONV_DIM * 2;   // 64 MiB (bf16)
  const size_t Z_B     = (size_t)MM * VALUE_DIM * 2;  // 32 MiB (bf16)
  ushort* mixed = (ushort*)wsb;
  ushort* qkv   = (ushort*)(wsb + MIXED_B);
  ushort* z     = (ushort*)(wsb + MIXED_B + QKV_B);
  float*  eg    = (float*)(wsb + MIXED_B + QKV_B + Z_B);
  float*  beta  = eg + (size_t)MM * NUM_V_HEADS;
  float*  o     = (float*)wsb;  // fp32, aliases retired mixed (exactly 64 MiB)

  gemm_f32_o<bf16><<<dim3(CONV_DIM / 64, MM / 64), 256, 0, stream>>>(
      hs, w_qkv, (bf16*)mixed, MM, CONV_DIM, HSZ);
  gemm_f32_o<bf16><<<dim3(VALUE_DIM / 64, MM / 64), 256, 0, stream>>>(
      hs, w_z, (bf16*)z, MM, VALUE_DIM, HSZ);
  ba_kernel<<<MM, 256, 0, stream>>>(hs, w_b, w_a, dt_bias, A_log, eg, beta);
  conv_kernel<<<MM, 256, 0, stream>>>(mixed, conv_w, qkv);
  recur_kernel<<<BB * NUM_V_HEADS * 4, 256, 0, stream>>>(qkv, eg, beta, o);
  gnorm_kernel<<<MM, 256, 0, stream>>>(o, z, gamma);
  gemm_f32_o<float><<<dim3(HSZ / 64, MM / 64), 256, 0, stream>>>(
      o, w_out, out, MM, HSZ, VALUE_DIM);
}

// Round 3
// 2935.178 us; speedup vs baseline: 2.2223x; 2.2223x over previous
//
#include <hip/hip_runtime.h>
#include <hip/hip_bf16.h>
#include <cstdint>

// ---------------------------------------------------------------------------
// Qwen3.5 GatedDeltaNet — round 3: bf16 MFMA GEMMs (m97 structure), scan as-is.
//   0) cast hs -> bf16; transpose+cast w_qkv, w_z, w_out -> N x K bf16
//   1) gemm_mfma: mixed(bf16) = hs_b @ w_qkv       (M4096 N8192 K2048)
//   2) gemm_mfma: z(bf16)     = hs_b @ w_z         (M4096 N4096 K2048)
//   3) ba_kernel: beta, eg
//   4) conv_kernel: causal conv(K=4) + silu + l2norm -> qkv (bf16)
//   5) recur_kernel: sequential gated delta rule -> o (fp32, aliases mixed)
//   6) gnorm_kernel: o *= silu(z); RMSNorm -> ob (bf16, aliases qkv)
//   7) gemm_mfma: out(fp32) = ob @ w_out           (M4096 N2048 K4096)
// Workspace: 241 MiB.
// ---------------------------------------------------------------------------

#define HSZ 2048
#define NUM_K_HEADS 16
#define NUM_V_HEADS 32
#define DKH 128
#define DVH 128
#define KEY_DIM 2048
#define VALUE_DIM 4096
#define CONV_DIM 8192
#define BB 2
#define SSEQ 2048
#define MM (BB * SSEQ) /* 4096 rows */

typedef __hip_bfloat16 bf16;
typedef short short8 __attribute__((ext_vector_type(8)));
typedef float f32x4 __attribute__((ext_vector_type(4)));

__device__ __forceinline__ float bfu(ushort u) {
  union { float f; uint32_t i; } x;
  x.i = ((uint32_t)u) << 16;
  return x.f;
}
__device__ __forceinline__ ushort f2b(float f) {
  bf16 h = __float2bfloat16(f);
  return *reinterpret_cast<ushort*>(&h);
}

__device__ __forceinline__ void gload16(const void* g, const void* l) {
  __builtin_amdgcn_global_load_lds(
      (const __attribute__((address_space(1))) unsigned int*)g,
      (__attribute__((address_space(3))) unsigned int*)(const_cast<void*>(l)),
      16, 0, 0);
}

// ---------------- cast fp32 -> bf16 (vectorized) ---------------------------
__global__ __launch_bounds__(256) void cast_bf16_kernel(
    const float* __restrict__ in, ushort* __restrict__ out, int n4) {
  int i = blockIdx.x * 256 + threadIdx.x;
  if (i < n4) {
    float4 v = ((const float4*)in)[i];
    ushort4 u;
    u.x = f2b(v.x); u.y = f2b(v.y); u.z = f2b(v.z); u.w = f2b(v.w);
    ((ushort4*)out)[i] = u;
  }
}

// ---------------- transpose + cast: W[K,N] fp32 -> WT[N,K] bf16 ------------
__global__ __launch_bounds__(256) void transpose_cast(
    const float* __restrict__ W, ushort* __restrict__ WT, int K, int N) {
  __shared__ ushort tile[32][33];
  const int tx = threadIdx.x & 31, ty = threadIdx.x >> 5;
  const int n0 = blockIdx.x * 32, k0 = blockIdx.y * 32;
#pragma unroll
  for (int i = 0; i < 4; ++i)
    tile[ty + i * 8][tx] = f2b(W[(size_t)(k0 + ty + i * 8) * N + n0 + tx]);
  __syncthreads();
#pragma unroll
  for (int i = 0; i < 4; ++i)
    WT[(size_t)(n0 + ty + i * 8) * K + k0 + tx] = tile[tx][ty + i * 8];
}

// ---------------- bf16 MFMA GEMM: C[M,N] = A[M,K] @ BT[N,K]^T --------------
// 128x128 tile, BK=64, 256 thr (4 waves 2x2), 4x4 16x16x32 frags per wave.
template <bool BF16_OUT>
__global__ __launch_bounds__(256) void gemm_mfma(
    const ushort* __restrict__ A, const ushort* __restrict__ BT,
    void* __restrict__ Cv, int M, int N, int K) {
  __shared__ ushort As[128 * 64];
  __shared__ ushort Bs[128 * 64];
  const int t = threadIdx.x;
  const int w = t >> 6, lane = t & 63;
  const int m0 = blockIdx.y * 128, n0 = blockIdx.x * 128;
  const int srow = lane >> 3;       // row within an 8-row chunk
  const int scol = (lane & 7) * 8;  // bf16 element offset (16B)
  const int wm = (w >> 1) * 64, wn = (w & 1) * 64;
  const int fr = lane & 15, kb = lane >> 4;
  f32x4 acc[4][4] = {};

  for (int k0 = 0; k0 < K; k0 += 64) {
#pragma unroll
    for (int i = 0; i < 4; ++i) {
      const int row = (i * 4 + w) * 8 + srow;  // 0..127, wave-contiguous 1KB
      gload16(&A[(size_t)(m0 + row) * K + k0 + scol], &As[row * 64 + scol]);
      gload16(&BT[(size_t)(n0 + row) * K + k0 + scol], &Bs[row * 64 + scol]);
    }
    __syncthreads();  // drains vmcnt -> LDS tiles ready
#pragma unroll
    for (int ks = 0; ks < 2; ++ks) {
      const int ka = ks * 32 + kb * 8;
      short8 af[4], bfr[4];
#pragma unroll
      for (int mf = 0; mf < 4; ++mf)
        af[mf] = *(const short8*)&As[(wm + mf * 16 + fr) * 64 + ka];
#pragma unroll
      for (int nf = 0; nf < 4; ++nf)
        bfr[nf] = *(const short8*)&Bs[(wn + nf * 16 + fr) * 64 + ka];
#pragma unroll
      for (int mf = 0; mf < 4; ++mf)
#pragma unroll
        for (int nf = 0; nf < 4; ++nf)
          acc[mf][nf] = __builtin_amdgcn_mfma_f32_16x16x32_bf16(
              af[mf], bfr[nf], acc[mf][nf], 0, 0, 0);
    }
    __syncthreads();
  }
  // epilogue: C row = (lane>>4)*4 + j, col = lane&15 (m89-verified mapping)
  const int orow = m0 + wm + (lane >> 4) * 4;
  const int ocol = n0 + wn + fr;
#pragma unroll
  for (int mf = 0; mf < 4; ++mf)
#pragma unroll
    for (int nf = 0; nf < 4; ++nf)
#pragma unroll
      for (int j = 0; j < 4; ++j) {
        const size_t off = (size_t)(orow + mf * 16 + j) * N + ocol + nf * 16;
        if constexpr (BF16_OUT)
          ((ushort*)Cv)[off] = f2b(acc[mf][nf][j]);
        else
          ((float*)Cv)[off] = acc[mf][nf][j];
      }
}

// ---------------- b/a projections + gates ----------------------------------
__global__ __launch_bounds__(256) void ba_kernel(
    const float* __restrict__ hs, const float* __restrict__ w_b,
    const float* __restrict__ w_a, const float* __restrict__ dt_bias,
    const float* __restrict__ A_log, float* __restrict__ eg,
    float* __restrict__ beta) {
  const int row = blockIdx.x;
  const int t = threadIdx.x;
  __shared__ float hsrow[HSZ];
  __shared__ float rb[256], ra[256];
  for (int c = t; c < HSZ; c += 256) hsrow[c] = hs[(size_t)row * HSZ + c];
  __syncthreads();
  const int h = t & 31, p = t >> 5;
  float sb = 0.f, sa = 0.f;
  const int kbeg = p * 256;
  for (int k = kbeg; k < kbeg + 256; ++k) {
    float x = hsrow[k];
    sb += x * w_b[k * NUM_V_HEADS + h];
    sa += x * w_a[k * NUM_V_HEADS + h];
  }
  rb[t] = sb;
  ra[t] = sa;
  __syncthreads();
  if (t < NUM_V_HEADS) {
    float b = 0.f, a = 0.f;
#pragma unroll
    for (int q = 0; q < 8; ++q) {
      b += rb[t + 32 * q];
      a += ra[t + 32 * q];
    }
    float bet = 1.f / (1.f + expf(-b));
    float x = a + dt_bias[t];
    float sp = (x > 20.f) ? x : log1pf(expf(x));
    float g = -expf(A_log[t]) * sp;
    eg[(size_t)row * NUM_V_HEADS + t] = expf(g);
    beta[(size_t)row * NUM_V_HEADS + t] = bet;
  }
}

// ---------------- causal conv + silu + l2norm (bf16 in/out) ----------------
__global__ __launch_bounds__(256) void conv_kernel(
    const ushort* __restrict__ mixed, const float* __restrict__ conv_w,
    ushort* __restrict__ qkv) {
  const int row = blockIdx.x;
  const int s = row & (SSEQ - 1);
  const int t = threadIdx.x;
  __shared__ float buf[CONV_DIM];
  const ushort* mrow = mixed + (size_t)row * CONV_DIM;
  for (int c = t; c < CONV_DIM; c += 256) {
    float accv = 0.f;
#pragma unroll
    for (int j = 0; j < 4; ++j) {
      int ds = s - 3 + j;
      if (ds >= 0)
        accv += bfu(mrow[(ptrdiff_t)(ds - s) * CONV_DIM + c]) * conv_w[c * 4 + j];
    }
    buf[c] = accv / (1.f + expf(-accv));
  }
  __syncthreads();
  const int grp = t >> 3, r = t & 7;
  const float* gp = buf + grp * DKH + r * 16;
  float ssq = 0.f;
#pragma unroll
  for (int i = 0; i < 16; ++i) {
    float x = gp[i];
    ssq += x * x;
  }
  ssq += __shfl_xor(ssq, 1, 64);
  ssq += __shfl_xor(ssq, 2, 64);
  ssq += __shfl_xor(ssq, 4, 64);
  float sc = rsqrtf(ssq + 1e-6f);
  if (grp < 16) sc *= 0.08838834764831845f;
  ushort* orow = qkv + (size_t)row * CONV_DIM;
#pragma unroll
  for (int i = 0; i < 16; ++i) orow[grp * DKH + r * 16 + i] = f2b(gp[i] * sc);
  for (int c = 2 * KEY_DIM + t; c < CONV_DIM; c += 256) orow[c] = f2b(buf[c]);
}

// ---------------- sequential gated delta rule ------------------------------
__global__ __launch_bounds__(256) void recur_kernel(
    const ushort* __restrict__ qkv, const float* __restrict__ eg,
    const float* __restrict__ beta, float* __restrict__ o) {
  const int bid = blockIdx.x;
  const int dvq = bid & 3;
  const int h = (bid >> 2) & 31;
  const int b = bid >> 7;
  const int t = threadIdx.x;
  const int tk = t & 15;
  const int tv = t >> 4;
  const int hk = h >> 1;

  const ushort* qp = qkv + (size_t)(b * SSEQ) * CONV_DIM + hk * DKH + tk * 8;
  const ushort* kp = qp + KEY_DIM;
  const ushort* vp = qkv + (size_t)(b * SSEQ) * CONV_DIM + 2 * KEY_DIM + h * DVH + dvq * 32 + tv * 2;
  const float* egp = eg + (size_t)(b * SSEQ) * NUM_V_HEADS + h;
  const float* bp = beta + (size_t)(b * SSEQ) * NUM_V_HEADS + h;
  float* op = o + (size_t)(b * SSEQ) * VALUE_DIM + h * DVH + dvq * 32 + tv * 2;

  float st0[8], st1[8];
#pragma unroll
  for (int i = 0; i < 8; ++i) {
    st0[i] = 0.f;
    st1[i] = 0.f;
  }

  for (int s = 0; s < SSEQ; ++s) {
    const size_t ro = (size_t)s * CONV_DIM;
    ushort4 qa = *(const ushort4*)(qp + ro);
    ushort4 qb = *(const ushort4*)(qp + ro + 4);
    ushort4 ka = *(const ushort4*)(kp + ro);
    ushort4 kb = *(const ushort4*)(kp + ro + 4);
    ushort2 vv = *(const ushort2*)(vp + ro);
    float e = egp[(size_t)s * NUM_V_HEADS];
    float bt = bp[(size_t)s * NUM_V_HEADS];
    float kf[8] = {bfu(ka.x), bfu(ka.y), bfu(ka.z), bfu(ka.w),
                   bfu(kb.x), bfu(kb.y), bfu(kb.z), bfu(kb.w)};
    float qf[8] = {bfu(qa.x), bfu(qa.y), bfu(qa.z), bfu(qa.w),
                   bfu(qb.x), bfu(qb.y), bfu(qb.z), bfu(qb.w)};
    float kv0 = 0.f, kv1 = 0.f;
#pragma unroll
    for (int i = 0; i < 8; ++i) {
      st0[i] *= e;
      st1[i] *= e;
      kv0 += kf[i] * st0[i];
      kv1 += kf[i] * st1[i];
    }
#pragma unroll
    for (int w = 1; w < 16; w <<= 1) {
      kv0 += __shfl_xor(kv0, w, 64);
      kv1 += __shfl_xor(kv1, w, 64);
    }
    float d0 = (bfu(vv.x) - kv0) * bt;
    float d1 = (bfu(vv.y) - kv1) * bt;
    float o0 = 0.f, o1 = 0.f;
#pragma unroll
    for (int i = 0; i < 8; ++i) {
      st0[i] += kf[i] * d0;
      o0 += qf[i] * st0[i];
      st1[i] += kf[i] * d1;
      o1 += qf[i] * st1[i];
    }
#pragma unroll
    for (int w = 1; w < 16; w <<= 1) {
      o0 += __shfl_xor(o0, w, 64);
      o1 += __shfl_xor(o1, w, 64);
    }
    if (tk == 0) {
      op[(size_t)s * VALUE_DIM + 0] = o0;
      op[(size_t)s * VALUE_DIM + 1] = o1;
    }
  }
}

// ---------------- gated RMSNorm -> bf16 ------------------------------------
__global__ __launch_bounds__(256) void gnorm_kernel(
    const float* __restrict__ o, const ushort* __restrict__ z,
    const float* __restrict__ gamma, ushort* __restrict__ ob) {
  const int row = blockIdx.x;
  const int t = threadIdx.x;
  const int grp = t >> 3, r = t & 7;
  const float* op = o + (size_t)row * VALUE_DIM + grp * DVH + r * 16;
  const ushort* zp = z + (size_t)row * VALUE_DIM + grp * DVH + r * 16;
  ushort* obp = ob + (size_t)row * VALUE_DIM + grp * DVH + r * 16;
  float vals[16];
  float ssq = 0.f;
#pragma unroll
  for (int i = 0; i < 16; ++i) {
    float zz = bfu(zp[i]);
    float x = op[i] * (zz / (1.f + expf(-zz)));
    vals[i] = x;
    ssq += x * x;
  }
  ssq += __shfl_xor(ssq, 1, 64);
  ssq += __shfl_xor(ssq, 2, 64);
  ssq += __shfl_xor(ssq, 4, 64);
  float sc = rsqrtf(ssq * (1.f / 128.f) + 1e-6f);
#pragma unroll
  for (int i = 0; i < 16; ++i) obp[i] = f2b(vals[i] * sc * gamma[r * 16 + i]);
}

// ---------------------------------------------------------------------------
extern "C" void kernel_launch(void* const* d_in, const int* in_sizes, int n_in,
                              void* d_out, int out_size, void* d_ws,
                              size_t ws_size, hipStream_t stream) {
  const float* hs = (const float*)d_in[0];
  const float* w_qkv = (const float*)d_in[1];
  const float* w_z = (const float*)d_in[2];
  const float* w_b = (const float*)d_in[3];
  const float* w_a = (const float*)d_in[4];
  const float* conv_w = (const float*)d_in[5];
  const float* dt_bias = (const float*)d_in[6];
  const float* A_log = (const float*)d_in[7];
  const float* gamma = (const float*)d_in[8];
  const float* w_out = (const float*)d_in[9];
  float* out = (float*)d_out;
  char* wsb = (char*)d_ws;

  // workspace layout (241 MiB total)
  ushort* hs_b  = (ushort*)wsb;                       // 16 MiB
  ushort* wqkvT = hs_b + (size_t)MM * HSZ;            // 32 MiB (8192 x 2048)
  ushort* wzT   = wqkvT + (size_t)CONV_DIM * HSZ;     // 16 MiB (4096 x 2048)
  ushort* woutT = wzT + (size_t)VALUE_DIM * HSZ;      // 16 MiB (2048 x 4096)
  ushort* mixed = woutT + (size_t)HSZ * VALUE_DIM;    // 64 MiB bf16
  ushort* qkv   = mixed + (size_t)MM * CONV_DIM;      // 64 MiB bf16
  ushort* z     = qkv + (size_t)MM * CONV_DIM;        // 32 MiB bf16
  float*  eg    = (float*)(z + (size_t)MM * VALUE_DIM);
  float*  beta  = eg + (size_t)MM * NUM_V_HEADS;
  float*  o     = (float*)mixed;  // fp32, aliases retired mixed (64 MiB)
  ushort* ob    = qkv;            // bf16, aliases retired qkv (32 MiB)

  cast_bf16_kernel<<<(MM * HSZ / 4 + 255) / 256, 256, 0, stream>>>(
      hs, hs_b, MM * HSZ / 4);
  transpose_cast<<<dim3(CONV_DIM / 32, HSZ / 32), 256, 0, stream>>>(
      w_qkv, wqkvT, HSZ, CONV_DIM);
  transpose_cast<<<dim3(VALUE_DIM / 32, HSZ / 32), 256, 0, stream>>>(
      w_z, wzT, HSZ, VALUE_DIM);
  transpose_cast<<<dim3(HSZ / 32, VALUE_DIM / 32), 256, 0, stream>>>(
      w_out, woutT, VALUE_DIM, HSZ);

  gemm_mfma<true><<<dim3(CONV_DIM / 128, MM / 128), 256, 0, stream>>>(
      hs_b, wqkvT, mixed, MM, CONV_DIM, HSZ);
  gemm_mfma<true><<<dim3(VALUE_DIM / 128, MM / 128), 256, 0, stream>>>(
      hs_b, wzT, z, MM, VALUE_DIM, HSZ);
  ba_kernel<<<MM, 256, 0, stream>>>(hs, w_b, w_a, dt_bias, A_log, eg, beta);
  conv_kernel<<<MM, 256, 0, stream>>>(mixed, conv_w, qkv);
  recur_kernel<<<BB * NUM_V_HEADS * 4, 256, 0, stream>>>(qkv, eg, beta, o);
  gnorm_kernel<<<MM, 256, 0, stream>>>(o, z, gamma, ob);
  gemm_mfma<false><<<dim3(HSZ / 128, MM / 128), 256, 0, stream>>>(
      ob, woutT, out, MM, HSZ, VALUE_DIM);
}

// Round 4
// 1140.170 us; speedup vs baseline: 5.7210x; 2.5743x over previous
//
#include <hip/hip_runtime.h>
#include <hip/hip_bf16.h>
#include <cstdint>

// ---------------------------------------------------------------------------
// Qwen3.5 GatedDeltaNet — round 4: chunked WY-form delta rule (MFMA),
// replacing the 2120 µs serial scan. GEMMs/conv/norm unchanged from round 3.
// ---------------------------------------------------------------------------

#define HSZ 2048
#define NUM_K_HEADS 16
#define NUM_V_HEADS 32
#define DKH 128
#define DVH 128
#define KEY_DIM 2048
#define VALUE_DIM 4096
#define CONV_DIM 8192
#define BB 2
#define SSEQ 2048
#define MM (BB * SSEQ) /* 4096 rows */
#define CHUNK 64
#define NCHUNK (SSEQ / CHUNK) /* 32 */

typedef __hip_bfloat16 bf16;
typedef short short8 __attribute__((ext_vector_type(8)));
typedef float f32x4 __attribute__((ext_vector_type(4)));

__device__ __forceinline__ float bfu(ushort u) {
  union { float f; uint32_t i; } x;
  x.i = ((uint32_t)u) << 16;
  return x.f;
}
__device__ __forceinline__ ushort f2b(float f) {
  bf16 h = __float2bfloat16(f);
  return *reinterpret_cast<ushort*>(&h);
}

__device__ __forceinline__ void gload16(const void* g, const void* l) {
  __builtin_amdgcn_global_load_lds(
      (const __attribute__((address_space(1))) unsigned int*)g,
      (__attribute__((address_space(3))) unsigned int*)(const_cast<void*>(l)),
      16, 0, 0);
}

// swizzled LDS indexers (break D=128/D=64 row-major bank pathology)
__device__ __forceinline__ int kidx(int r, int d) {  // [*][128] bf16
  return r * 128 + (((d >> 3) ^ (r & 7)) << 3) + (d & 7);
}
__device__ __forceinline__ int widx(int r, int d) {  // [*][64] bf16
  return r * 64 + (((d >> 3) ^ (r & 7)) << 3) + (d & 7);
}

// ---------------- cast fp32 -> bf16 ----------------------------------------
__global__ __launch_bounds__(256) void cast_bf16_kernel(
    const float* __restrict__ in, ushort* __restrict__ out, int n4) {
  int i = blockIdx.x * 256 + threadIdx.x;
  if (i < n4) {
    float4 v = ((const float4*)in)[i];
    ushort4 u;
    u.x = f2b(v.x); u.y = f2b(v.y); u.z = f2b(v.z); u.w = f2b(v.w);
    ((ushort4*)out)[i] = u;
  }
}

// ---------------- transpose + cast: W[K,N] fp32 -> WT[N,K] bf16 ------------
__global__ __launch_bounds__(256) void transpose_cast(
    const float* __restrict__ W, ushort* __restrict__ WT, int K, int N) {
  __shared__ ushort tile[32][33];
  const int tx = threadIdx.x & 31, ty = threadIdx.x >> 5;
  const int n0 = blockIdx.x * 32, k0 = blockIdx.y * 32;
#pragma unroll
  for (int i = 0; i < 4; ++i)
    tile[ty + i * 8][tx] = f2b(W[(size_t)(k0 + ty + i * 8) * N + n0 + tx]);
  __syncthreads();
#pragma unroll
  for (int i = 0; i < 4; ++i)
    WT[(size_t)(n0 + ty + i * 8) * K + k0 + tx] = tile[tx][ty + i * 8];
}

// ---------------- bf16 MFMA GEMM: C[M,N] = A[M,K] @ BT[N,K]^T --------------
template <bool BF16_OUT>
__global__ __launch_bounds__(256) void gemm_mfma(
    const ushort* __restrict__ A, const ushort* __restrict__ BT,
    void* __restrict__ Cv, int M, int N, int K) {
  __shared__ ushort As[128 * 64];
  __shared__ ushort Bs[128 * 64];
  const int t = threadIdx.x;
  const int w = t >> 6, lane = t & 63;
  const int m0 = blockIdx.y * 128, n0 = blockIdx.x * 128;
  const int srow = lane >> 3;
  const int scol = (lane & 7) * 8;
  const int wm = (w >> 1) * 64, wn = (w & 1) * 64;
  const int fr = lane & 15, kb = lane >> 4;
  f32x4 acc[4][4] = {};

  for (int k0 = 0; k0 < K; k0 += 64) {
#pragma unroll
    for (int i = 0; i < 4; ++i) {
      const int row = (i * 4 + w) * 8 + srow;
      gload16(&A[(size_t)(m0 + row) * K + k0 + scol], &As[row * 64 + scol]);
      gload16(&BT[(size_t)(n0 + row) * K + k0 + scol], &Bs[row * 64 + scol]);
    }
    __syncthreads();
#pragma unroll
    for (int ks = 0; ks < 2; ++ks) {
      const int ka = ks * 32 + kb * 8;
      short8 af[4], bfr[4];
#pragma unroll
      for (int mf = 0; mf < 4; ++mf)
        af[mf] = *(const short8*)&As[(wm + mf * 16 + fr) * 64 + ka];
#pragma unroll
      for (int nf = 0; nf < 4; ++nf)
        bfr[nf] = *(const short8*)&Bs[(wn + nf * 16 + fr) * 64 + ka];
#pragma unroll
      for (int mf = 0; mf < 4; ++mf)
#pragma unroll
        for (int nf = 0; nf < 4; ++nf)
          acc[mf][nf] = __builtin_amdgcn_mfma_f32_16x16x32_bf16(
              af[mf], bfr[nf], acc[mf][nf], 0, 0, 0);
    }
    __syncthreads();
  }
  const int orow = m0 + wm + (lane >> 4) * 4;
  const int ocol = n0 + wn + fr;
#pragma unroll
  for (int mf = 0; mf < 4; ++mf)
#pragma unroll
    for (int nf = 0; nf < 4; ++nf)
#pragma unroll
      for (int j = 0; j < 4; ++j) {
        const size_t off = (size_t)(orow + mf * 16 + j) * N + ocol + nf * 16;
        if constexpr (BF16_OUT)
          ((ushort*)Cv)[off] = f2b(acc[mf][nf][j]);
        else
          ((float*)Cv)[off] = acc[mf][nf][j];
      }
}

// ---------------- b/a projections + gates (g = log decay) ------------------
__global__ __launch_bounds__(256) void ba_kernel(
    const float* __restrict__ hs, const float* __restrict__ w_b,
    const float* __restrict__ w_a, const float* __restrict__ dt_bias,
    const float* __restrict__ A_log, float* __restrict__ gbuf,
    float* __restrict__ beta) {
  const int row = blockIdx.x;
  const int t = threadIdx.x;
  __shared__ float hsrow[HSZ];
  __shared__ float rb[256], ra[256];
  for (int c = t; c < HSZ; c += 256) hsrow[c] = hs[(size_t)row * HSZ + c];
  __syncthreads();
  const int h = t & 31, p = t >> 5;
  float sb = 0.f, sa = 0.f;
  const int kbeg = p * 256;
  for (int k = kbeg; k < kbeg + 256; ++k) {
    float x = hsrow[k];
    sb += x * w_b[k * NUM_V_HEADS + h];
    sa += x * w_a[k * NUM_V_HEADS + h];
  }
  rb[t] = sb;
  ra[t] = sa;
  __syncthreads();
  if (t < NUM_V_HEADS) {
    float b = 0.f, a = 0.f;
#pragma unroll
    for (int q = 0; q < 8; ++q) {
      b += rb[t + 32 * q];
      a += ra[t + 32 * q];
    }
    float bet = 1.f / (1.f + expf(-b));
    float x = a + dt_bias[t];
    float sp = (x > 20.f) ? x : log1pf(expf(x));
    gbuf[(size_t)row * NUM_V_HEADS + t] = -expf(A_log[t]) * sp;
    beta[(size_t)row * NUM_V_HEADS + t] = bet;
  }
}

// ---------------- causal conv + silu + l2norm (bf16) -----------------------
__global__ __launch_bounds__(256) void conv_kernel(
    const ushort* __restrict__ mixed, const float* __restrict__ conv_w,
    ushort* __restrict__ qkv) {
  const int row = blockIdx.x;
  const int s = row & (SSEQ - 1);
  const int t = threadIdx.x;
  __shared__ float buf[CONV_DIM];
  const ushort* mrow = mixed + (size_t)row * CONV_DIM;
  for (int c = t; c < CONV_DIM; c += 256) {
    float accv = 0.f;
#pragma unroll
    for (int j = 0; j < 4; ++j) {
      int ds = s - 3 + j;
      if (ds >= 0)
        accv += bfu(mrow[(ptrdiff_t)(ds - s) * CONV_DIM + c]) * conv_w[c * 4 + j];
    }
    buf[c] = accv / (1.f + expf(-accv));
  }
  __syncthreads();
  const int grp = t >> 3, r = t & 7;
  const float* gp = buf + grp * DKH + r * 16;
  float ssq = 0.f;
#pragma unroll
  for (int i = 0; i < 16; ++i) {
    float x = gp[i];
    ssq += x * x;
  }
  ssq += __shfl_xor(ssq, 1, 64);
  ssq += __shfl_xor(ssq, 2, 64);
  ssq += __shfl_xor(ssq, 4, 64);
  float sc = rsqrtf(ssq + 1e-6f);
  if (grp < 16) sc *= 0.08838834764831845f;
  ushort* orow = qkv + (size_t)row * CONV_DIM;
#pragma unroll
  for (int i = 0; i < 16; ++i) orow[grp * DKH + r * 16 + i] = f2b(gp[i] * sc);
  for (int c = 2 * KEY_DIM + t; c < CONV_DIM; c += 256) orow[c] = f2b(buf[c]);
}

// ---------------- chunked gated delta rule (WY form) -----------------------
// grid = 256 blocks: (b:2) x (h:32) x (dvq:4, 32 v-cols each). 256 thr.
__global__ __launch_bounds__(256) void recur_chunk_kernel(
    const ushort* __restrict__ qkv, const float* __restrict__ gbuf,
    const float* __restrict__ beta, float* __restrict__ o) {
  const int bid = blockIdx.x;
  const int dvq = bid & 3;
  const int h = (bid >> 2) & 31;
  const int b = bid >> 7;
  const int hk = h >> 1;
  const int t = threadIdx.x;
  const int w = t >> 6, lane = t & 63;
  const int fr = lane & 15, fq = lane >> 4;

  __shared__ ushort Klds[64 * 128];
  __shared__ ushort Qlds[64 * 128];
  __shared__ ushort Vlds[64 * 32];
  __shared__ float Slds[128 * 32];
  __shared__ ushort Sth[32 * 128];
  __shared__ ushort Stl[32 * 128];
  __shared__ float Alds[64 * 64];
  __shared__ float Ulds[64 * 32];
  __shared__ ushort UTs[32 * 64];  // exp(G63-Gi)*u — state update operand
  __shared__ ushort UTo[32 * 64];  // plain u — output operand
  __shared__ ushort Wb[64 * 64];
  __shared__ float Gs[64], Bsh[64];

  for (int i = t; i < 128 * 32; i += 256) Slds[i] = 0.f;
  __syncthreads();

  const int qcol = hk * DKH;
  const int kcol = KEY_DIM + hk * DKH;
  const int vcol = 2 * KEY_DIM + h * DVH + dvq * 32;

  for (int c = 0; c < NCHUNK; ++c) {
    const int row0 = b * SSEQ + c * CHUNK;

    // ---- phase 1: load K/Q (swizzled), V; gates + scan; S -> hi/lo -------
#pragma unroll
    for (int r = 0; r < 4; ++r) {
      int vi = t + 256 * r;
      int row = vi >> 4, gr = vi & 15;
      const size_t gb = (size_t)(row0 + row) * CONV_DIM;
      short8 kv = *(const short8*)&qkv[gb + kcol + gr * 8];
      short8 qv = *(const short8*)&qkv[gb + qcol + gr * 8];
      *(short8*)&Klds[row * 128 + ((gr ^ (row & 7)) << 3)] = kv;
      *(short8*)&Qlds[row * 128 + ((gr ^ (row & 7)) << 3)] = qv;
    }
    {
      int row = t >> 2, gr = t & 3;
      *(short8*)&Vlds[row * 32 + gr * 8] =
          *(const short8*)&qkv[(size_t)(row0 + row) * CONV_DIM + vcol + gr * 8];
    }
    if (t < 64) {
      float s = gbuf[(size_t)(row0 + t) * NUM_V_HEADS + h];
#pragma unroll
      for (int off = 1; off < 64; off <<= 1) {
        float p = __shfl_up(s, off, 64);
        if (lane >= off) s += p;
      }
      Gs[t] = s;
      Bsh[t] = beta[(size_t)(row0 + t) * NUM_V_HEADS + h];
    }
    {
      int v = t & 31, dk0 = (t >> 5) * 16;
#pragma unroll
      for (int e = 0; e < 16; ++e) {
        int d = dk0 + e;
        float f = Slds[d * 32 + v];
        ushort hi = f2b(f);
        float rem = f - bfu(hi);
        int idx = kidx(v, d);
        Sth[idx] = hi;
        Stl[idx] = f2b(rem);
      }
    }
    __syncthreads();

    // ---- phase 2: KK^T -> A ; K@S0 -> U init -----------------------------
    {
      f32x4 kkt[4] = {};
      f32x4 ks0[2] = {};
#pragma unroll
      for (int ks = 0; ks < 4; ++ks) {
        int d0 = ks * 32 + fq * 8;
        short8 xk = *(const short8*)&Klds[kidx(w * 16 + fr, d0)];
#pragma unroll
        for (int j = 0; j < 4; ++j) {
          short8 yk = *(const short8*)&Klds[kidx(j * 16 + fr, d0)];
          kkt[j] = __builtin_amdgcn_mfma_f32_16x16x32_bf16(xk, yk, kkt[j], 0, 0, 0);
        }
#pragma unroll
        for (int vt = 0; vt < 2; ++vt) {
          short8 yh = *(const short8*)&Sth[kidx(vt * 16 + fr, d0)];
          short8 yl = *(const short8*)&Stl[kidx(vt * 16 + fr, d0)];
          ks0[vt] = __builtin_amdgcn_mfma_f32_16x16x32_bf16(xk, yh, ks0[vt], 0, 0, 0);
          ks0[vt] = __builtin_amdgcn_mfma_f32_16x16x32_bf16(xk, yl, ks0[vt], 0, 0, 0);
        }
      }
#pragma unroll
      for (int j = 0; j < 4; ++j)
#pragma unroll
        for (int jj = 0; jj < 4; ++jj) {
          int i = w * 16 + fq * 4 + jj;
          int jc = j * 16 + fr;
          Alds[i * 64 + jc] =
              (jc < i) ? Bsh[i] * __expf(Gs[i] - Gs[jc]) * kkt[j][jj] : 0.f;
        }
#pragma unroll
      for (int vt = 0; vt < 2; ++vt)
#pragma unroll
        for (int jj = 0; jj < 4; ++jj) {
          int i = w * 16 + fq * 4 + jj;
          int v = vt * 16 + fr;
          Ulds[i * 32 + v] =
              Bsh[i] * (bfu(Vlds[i * 32 + v]) - __expf(Gs[i]) * ks0[vt][jj]);
        }
    }
    __syncthreads();

    // ---- phase 3: forward substitution (I+A) U = RHS ---------------------
#pragma unroll
    for (int ib = 0; ib < 4; ++ib) {
      if (ib > 0) {
        int r = t >> 4, c0 = (t & 15) * 2;
        int irow = ib * 16 + r;
        float a0 = 0.f, a1 = 0.f;
        for (int j = 0; j < ib * 16; ++j) {
          float a = Alds[irow * 64 + j];
          a0 += a * Ulds[j * 32 + c0];
          a1 += a * Ulds[j * 32 + c0 + 1];
        }
        Ulds[irow * 32 + c0] -= a0;
        Ulds[irow * 32 + c0 + 1] -= a1;
      }
      __syncthreads();
      if (t < 32) {
        for (int ii = 1; ii < 16; ++ii) {
          int i = ib * 16 + ii;
          float s = 0.f;
          for (int j = ib * 16; j < i; ++j)
            s += Alds[i * 64 + j] * Ulds[j * 32 + t];
          Ulds[i * 32 + t] -= s;
        }
      }
      __syncthreads();
    }

    // ---- phase 4: U transposes; QK^T -> W; Q@S0 --------------------------
    {
      int i = t & 63, v0 = (t >> 6) * 8;
      float sc = __expf(Gs[63] - Gs[i]);
#pragma unroll
      for (int e = 0; e < 8; ++e) {
        float u = Ulds[i * 32 + v0 + e];
        int idx = widx(v0 + e, i);
        UTs[idx] = f2b(u * sc);
        UTo[idx] = f2b(u);
      }
    }
    f32x4 oacc[2] = {};
    {
      f32x4 qkt[4] = {};
#pragma unroll
      for (int ks = 0; ks < 4; ++ks) {
        int d0 = ks * 32 + fq * 8;
        short8 xq = *(const short8*)&Qlds[kidx(w * 16 + fr, d0)];
#pragma unroll
        for (int j = 0; j < 4; ++j) {
          short8 yk = *(const short8*)&Klds[kidx(j * 16 + fr, d0)];
          qkt[j] = __builtin_amdgcn_mfma_f32_16x16x32_bf16(xq, yk, qkt[j], 0, 0, 0);
        }
#pragma unroll
        for (int vt = 0; vt < 2; ++vt) {
          short8 yh = *(const short8*)&Sth[kidx(vt * 16 + fr, d0)];
          short8 yl = *(const short8*)&Stl[kidx(vt * 16 + fr, d0)];
          oacc[vt] = __builtin_amdgcn_mfma_f32_16x16x32_bf16(xq, yh, oacc[vt], 0, 0, 0);
          oacc[vt] = __builtin_amdgcn_mfma_f32_16x16x32_bf16(xq, yl, oacc[vt], 0, 0, 0);
        }
      }
#pragma unroll
      for (int j = 0; j < 4; ++j)
#pragma unroll
        for (int jj = 0; jj < 4; ++jj) {
          int tt = w * 16 + fq * 4 + jj;
          int i = j * 16 + fr;
          float val = (i <= tt) ? __expf(Gs[tt] - Gs[i]) * qkt[j][jj] : 0.f;
          Wb[widx(tt, i)] = f2b(val);
        }
#pragma unroll
      for (int vt = 0; vt < 2; ++vt)
#pragma unroll
        for (int jj = 0; jj < 4; ++jj)
          oacc[vt][jj] *= __expf(Gs[w * 16 + fq * 4 + jj]);
    }
    __syncthreads();

    // ---- phase 5: O = Lt*(QS0) + W @ U ; store; scale S ------------------
#pragma unroll
    for (int ks = 0; ks < 2; ++ks) {
      int i0 = ks * 32 + fq * 8;
      int trow = w * 16 + fr;
      short8 xw = *(const short8*)&Wb[trow * 64 + (((i0 >> 3) ^ (trow & 7)) << 3)];
#pragma unroll
      for (int vt = 0; vt < 2; ++vt) {
        int vrow = vt * 16 + fr;
        short8 yu = *(const short8*)&UTo[vrow * 64 + (((i0 >> 3) ^ (vrow & 7)) << 3)];
        oacc[vt] = __builtin_amdgcn_mfma_f32_16x16x32_bf16(xw, yu, oacc[vt], 0, 0, 0);
      }
    }
#pragma unroll
    for (int vt = 0; vt < 2; ++vt)
#pragma unroll
      for (int jj = 0; jj < 4; ++jj) {
        int tt = w * 16 + fq * 4 + jj;
        o[(size_t)(row0 + tt) * VALUE_DIM + h * DVH + dvq * 32 + vt * 16 + fr] =
            oacc[vt][jj];
      }
    {
      float eGC = __expf(Gs[63]);
      for (int i = t; i < 128 * 32; i += 256) Slds[i] *= eGC;
    }
    __syncthreads();

    // ---- phase 6: S += K^T @ Us ------------------------------------------
    {
      f32x4 sacc[2][2];
#pragma unroll
      for (int dt = 0; dt < 2; ++dt) {
        int dk0 = (w * 2 + dt) * 16;
#pragma unroll
        for (int vt = 0; vt < 2; ++vt)
#pragma unroll
          for (int jj = 0; jj < 4; ++jj)
            sacc[dt][vt][jj] = Slds[(dk0 + fq * 4 + jj) * 32 + vt * 16 + fr];
#pragma unroll
        for (int ks = 0; ks < 2; ++ks) {
          short8 xk;
          int dkr = dk0 + fr;
#pragma unroll
          for (int e = 0; e < 8; ++e)
            xk[e] = (short)Klds[kidx(ks * 32 + fq * 8 + e, dkr)];
#pragma unroll
          for (int vt = 0; vt < 2; ++vt) {
            int vrow = vt * 16 + fr;
            int i0 = ks * 32 + fq * 8;
            short8 yu =
                *(const short8*)&UTs[vrow * 64 + (((i0 >> 3) ^ (vrow & 7)) << 3)];
            sacc[dt][vt] = __builtin_amdgcn_mfma_f32_16x16x32_bf16(
                xk, yu, sacc[dt][vt], 0, 0, 0);
          }
        }
#pragma unroll
        for (int vt = 0; vt < 2; ++vt)
#pragma unroll
          for (int jj = 0; jj < 4; ++jj)
            Slds[(dk0 + fq * 4 + jj) * 32 + vt * 16 + fr] = sacc[dt][vt][jj];
      }
    }
    __syncthreads();
  }
}

// ---------------- gated RMSNorm -> bf16 ------------------------------------
__global__ __launch_bounds__(256) void gnorm_kernel(
    const float* __restrict__ o, const ushort* __restrict__ z,
    const float* __restrict__ gamma, ushort* __restrict__ ob) {
  const int row = blockIdx.x;
  const int t = threadIdx.x;
  const int grp = t >> 3, r = t & 7;
  const float* op = o + (size_t)row * VALUE_DIM + grp * DVH + r * 16;
  const ushort* zp = z + (size_t)row * VALUE_DIM + grp * DVH + r * 16;
  ushort* obp = ob + (size_t)row * VALUE_DIM + grp * DVH + r * 16;
  float vals[16];
  float ssq = 0.f;
#pragma unroll
  for (int i = 0; i < 16; ++i) {
    float zz = bfu(zp[i]);
    float x = op[i] * (zz / (1.f + expf(-zz)));
    vals[i] = x;
    ssq += x * x;
  }
  ssq += __shfl_xor(ssq, 1, 64);
  ssq += __shfl_xor(ssq, 2, 64);
  ssq += __shfl_xor(ssq, 4, 64);
  float sc = rsqrtf(ssq * (1.f / 128.f) + 1e-6f);
#pragma unroll
  for (int i = 0; i < 16; ++i) obp[i] = f2b(vals[i] * sc * gamma[r * 16 + i]);
}

// ---------------------------------------------------------------------------
extern "C" void kernel_launch(void* const* d_in, const int* in_sizes, int n_in,
                              void* d_out, int out_size, void* d_ws,
                              size_t ws_size, hipStream_t stream) {
  const float* hs = (const float*)d_in[0];
  const float* w_qkv = (const float*)d_in[1];
  const float* w_z = (const float*)d_in[2];
  const float* w_b = (const float*)d_in[3];
  const float* w_a = (const float*)d_in[4];
  const float* conv_w = (const float*)d_in[5];
  const float* dt_bias = (const float*)d_in[6];
  const float* A_log = (const float*)d_in[7];
  const float* gamma = (const float*)d_in[8];
  const float* w_out = (const float*)d_in[9];
  float* out = (float*)d_out;
  char* wsb = (char*)d_ws;

  // workspace layout (241 MiB total)
  ushort* hs_b = (ushort*)wsb;                      // 16 MiB
  ushort* wqkvT = hs_b + (size_t)MM * HSZ;          // 32 MiB
  ushort* wzT = wqkvT + (size_t)CONV_DIM * HSZ;     // 16 MiB
  ushort* woutT = wzT + (size_t)VALUE_DIM * HSZ;    // 16 MiB
  ushort* mixed = woutT + (size_t)HSZ * VALUE_DIM;  // 64 MiB bf16
  ushort* qkv = mixed + (size_t)MM * CONV_DIM;      // 64 MiB bf16
  ushort* z = qkv + (size_t)MM * CONV_DIM;          // 32 MiB bf16
  float* gbuf = (float*)(z + (size_t)MM * VALUE_DIM);
  float* beta = gbuf + (size_t)MM * NUM_V_HEADS;
  float* o = (float*)mixed;  // fp32, aliases retired mixed (64 MiB)
  ushort* ob = qkv;          // bf16, aliases retired qkv

  cast_bf16_kernel<<<(MM * HSZ / 4 + 255) / 256, 256, 0, stream>>>(
      hs, hs_b, MM * HSZ / 4);
  transpose_cast<<<dim3(CONV_DIM / 32, HSZ / 32), 256, 0, stream>>>(
      w_qkv, wqkvT, HSZ, CONV_DIM);
  transpose_cast<<<dim3(VALUE_DIM / 32, HSZ / 32), 256, 0, stream>>>(
      w_z, wzT, HSZ, VALUE_DIM);
  transpose_cast<<<dim3(HSZ / 32, VALUE_DIM / 32), 256, 0, stream>>>(
      w_out, woutT, VALUE_DIM, HSZ);

  gemm_mfma<true><<<dim3(CONV_DIM / 128, MM / 128), 256, 0, stream>>>(
      hs_b, wqkvT, mixed, MM, CONV_DIM, HSZ);
  gemm_mfma<true><<<dim3(VALUE_DIM / 128, MM / 128), 256, 0, stream>>>(
      hs_b, wzT, z, MM, VALUE_DIM, HSZ);
  ba_kernel<<<MM, 256, 0, stream>>>(hs, w_b, w_a, dt_bias, A_log, gbuf, beta);
  conv_kernel<<<MM, 256, 0, stream>>>(mixed, conv_w, qkv);
  recur_chunk_kernel<<<256, 256, 0, stream>>>(qkv, gbuf, beta, o);
  gnorm_kernel<<<MM, 256, 0, stream>>>(o, z, gamma, ob);
  gemm_mfma<false><<<dim3(HSZ / 128, MM / 128), 256, 0, stream>>>(
      ob, woutT, out, MM, HSZ, VALUE_DIM);
}